// Round 3
// baseline (6158.253 us; speedup 1.0000x reference)
//
#include <hip/hip_runtime.h>
#include <hip/hip_bf16.h>
#include <math.h>

#define Bn 8
#define Tn 898
#define Dn 1024
#define Hn 16
#define DHn 64
#define Ln 12
#define FFn 4096
#define Vn 1024
#define BT (Bn*Tn)   /* 7184 */
#define MP 7424      /* BT padded to 29*256 */

typedef short bf16x8 __attribute__((ext_vector_type(8)));
typedef float f32x4 __attribute__((ext_vector_type(4)));

__device__ __forceinline__ ushort f2bf(float f) {
    union { float f; unsigned u; } c; c.f = f;
    unsigned r = c.u + 0x7fffu + ((c.u >> 16) & 1u);
    return (ushort)(r >> 16);
}

__device__ __forceinline__ void glds16(const void* g, void* l) {
    __builtin_amdgcn_global_load_lds(
        (const __attribute__((address_space(1))) unsigned int*)g,
        (__attribute__((address_space(3))) unsigned int*)l, 16, 0, 0);
}

// ---------------- weight transpose + cast: f32 [K][N] -> bf16 [N][K] ----------------
__global__ __launch_bounds__(256) void transpose_cast_kernel(
    const float* __restrict__ in, ushort* __restrict__ out,
    int K, int N, size_t in_ls, size_t out_ls)
{
    __shared__ ushort t[64][68];
    const float* inp = in + (size_t)blockIdx.z * in_ls;
    ushort* outp = out + (size_t)blockIdx.z * out_ls;
    int n0 = blockIdx.x * 64, k0 = blockIdx.y * 64;
    int tx = threadIdx.x & 63, ty = threadIdx.x >> 6;
    #pragma unroll
    for (int p = 0; p < 16; p++) {
        int kl = p * 4 + ty;
        t[tx][kl] = f2bf(inp[(size_t)(k0 + kl) * N + n0 + tx]);
    }
    __syncthreads();
    int tx4 = threadIdx.x & 15, ty4 = threadIdx.x >> 4;
    #pragma unroll
    for (int p = 0; p < 4; p++) {
        int nl = p * 16 + ty4;
        ushort4 v;
        v.x = t[nl][4*tx4]; v.y = t[nl][4*tx4+1]; v.z = t[nl][4*tx4+2]; v.w = t[nl][4*tx4+3];
        *(ushort4*)&outp[(size_t)(n0 + nl) * K + k0 + 4*tx4] = v;
    }
}

// ---------------- embedding + positional encoding ----------------
__global__ __launch_bounds__(256) void embed_kernel(
    const int* __restrict__ tids, const int* __restrict__ pids, const int* __restrict__ oids,
    const float* __restrict__ ttab, const float* __restrict__ ptab, const float* __restrict__ otab,
    const float* __restrict__ sep, float* __restrict__ x)
{
    int bp = blockIdx.x;
    int b = bp / Tn, pos = bp - b * Tn;
    int d0 = threadIdx.x * 4;
    float4 r;
    if (pos == 128 || pos == 385) {
        r = *(const float4*)(sep + d0);
    } else {
        int t; int id; const float* tab;
        if (pos < 128)      { t = pos;       id = tids[b*128 + t]; tab = ttab; }
        else if (pos < 385) { t = pos - 129; id = pids[b*256 + t]; tab = ptab; }
        else                { t = pos - 386; id = oids[b*512 + t]; tab = otab; }
        float4 e = *(const float4*)(tab + (size_t)id * Dn + d0);
        float pe[4];
        #pragma unroll
        for (int i = 0; i < 4; i++) {
            int d = d0 + i;
            int ii = d & 511;
            float omega = expf(-9.210340371976184f * (float)ii * (1.0f/512.0f));
            float ang = (float)t * omega;
            pe[i] = (d < 512) ? sinf(ang) : cosf(ang);
        }
        r.x = e.x + pe[0]; r.y = e.y + pe[1]; r.z = e.z + pe[2]; r.w = e.w + pe[3];
    }
    *(float4*)(x + (size_t)bp * Dn + d0) = r;
}

// ---------------- layernorm fp32 -> bf16 ----------------
__global__ __launch_bounds__(256) void ln_kernel(
    const float* __restrict__ x, const float* __restrict__ g, const float* __restrict__ bt,
    ushort* __restrict__ out)
{
    __shared__ float red[8];
    int row = blockIdx.x, tid = threadIdx.x;
    float4 v = ((const float4*)(x + (size_t)row * Dn))[tid];
    float s = v.x + v.y + v.z + v.w;
    #pragma unroll
    for (int o = 32; o; o >>= 1) s += __shfl_down(s, o);
    if ((tid & 63) == 0) red[tid >> 6] = s;
    __syncthreads();
    float mu = (red[0] + red[1] + red[2] + red[3]) * (1.0f / Dn);
    float d0 = v.x - mu, d1 = v.y - mu, d2 = v.z - mu, d3 = v.w - mu;
    float s2 = d0*d0 + d1*d1 + d2*d2 + d3*d3;
    #pragma unroll
    for (int o = 32; o; o >>= 1) s2 += __shfl_down(s2, o);
    if ((tid & 63) == 0) red[4 + (tid >> 6)] = s2;
    __syncthreads();
    float var = (red[4] + red[5] + red[6] + red[7]) * (1.0f / Dn);
    float rstd = rsqrtf(var + 1e-5f);
    float4 gg = ((const float4*)g)[tid];
    float4 bb = ((const float4*)bt)[tid];
    ushort4 o4;
    o4.x = f2bf(d0 * rstd * gg.x + bb.x);
    o4.y = f2bf(d1 * rstd * gg.y + bb.y);
    o4.z = f2bf(d2 * rstd * gg.z + bb.z);
    o4.w = f2bf(d3 * rstd * gg.w + bb.w);
    ((ushort4*)(out + (size_t)row * Dn))[tid] = o4;
}

// ---------------- 2-phase double-buffered GEMM: C = A(bf16 [M][K]) @ Bw(bf16 [N][K])^T --------
// MODE 0: store bf16; MODE 1: f32 = resid + AB + bias; MODE 2: bf16 = gelu(AB + bias)
template<int BM, int BN, int WM, int WN, int MODE>
__global__ __launch_bounds__(WM*WN*64) void gemm2_kernel(
    const ushort* __restrict__ A, const ushort* __restrict__ Bw,
    const float* __restrict__ bias, const float* __restrict__ resid,
    void* __restrict__ Cout, int M, int N, int K, int nx)
{
    constexpr int NWAVE = WM * WN;
    constexpr int MI = BM / WM / 16;
    constexpr int NI = BN / WN / 16;
    constexpr int GA = (BM / 8) / NWAVE;   // glds instrs per thread for A
    constexpr int GB = (BN / 8) / NWAVE;

    __shared__ ushort sA[2][BM * 64];
    __shared__ ushort sB[2][BN * 64];

    int tid = threadIdx.x, lane = tid & 63, wv = tid >> 6;
    int wm = wv / WN, wn = wv % WN;
    int l16 = lane & 15, lhi = lane >> 4;

    // bijective XCD-chunked swizzle (m204)
    int nb = gridDim.x, bid = blockIdx.x;
    int q = nb >> 3, r = nb & 7;
    int xcd = bid & 7, idx = bid >> 3;
    int wg = (xcd < r ? xcd * (q + 1) : r * (q + 1) + (xcd - r) * q) + idx;
    int mt = wg / nx, ntt = wg - mt * nx;
    int m0 = mt * BM, n0 = ntt * BN;

    f32x4 acc[MI][NI];
    #pragma unroll
    for (int i = 0; i < MI; i++)
        #pragma unroll
        for (int j = 0; j < NI; j++) acc[i][j] = (f32x4){0.f, 0.f, 0.f, 0.f};

    const int sr = lane >> 3;            // row in 8-row group
    const int sc = (lane & 7) * 8;       // ushort col in row
    const ushort* Ab = A + (size_t)m0 * K + sc;
    const ushort* Bb = Bw + (size_t)n0 * K + sc;

    auto STAGE = [&](int buf, int kk) {
        #pragma unroll
        for (int i = 0; i < GA; i++) {
            int rg = wv * GA + i;
            glds16(Ab + (size_t)(rg * 8 + sr) * K + kk, &sA[buf][rg * 512]);
        }
        #pragma unroll
        for (int i = 0; i < GB; i++) {
            int rg = wv * GB + i;
            glds16(Bb + (size_t)(rg * 8 + sr) * K + kk, &sB[buf][rg * 512]);
        }
    };

    auto COMPUTE = [&](int buf) {
        #pragma unroll
        for (int ks = 0; ks < 2; ks++) {
            bf16x8 af[MI], bfr[NI];
            #pragma unroll
            for (int mi = 0; mi < MI; mi++)
                af[mi] = *(const bf16x8*)&sA[buf][(wm * (16 * MI) + mi * 16 + l16) * 64 + ks * 32 + lhi * 8];
            #pragma unroll
            for (int ni = 0; ni < NI; ni++)
                bfr[ni] = *(const bf16x8*)&sB[buf][(wn * (16 * NI) + ni * 16 + l16) * 64 + ks * 32 + lhi * 8];
            #pragma unroll
            for (int mi = 0; mi < MI; mi++)
                #pragma unroll
                for (int ni = 0; ni < NI; ni++)
                    acc[mi][ni] = __builtin_amdgcn_mfma_f32_16x16x32_bf16(af[mi], bfr[ni], acc[mi][ni], 0, 0, 0);
        }
    };

    int ntile = K >> 6;
    STAGE(0, 0);
    __syncthreads();
    int cur = 0;
    for (int t = 0; t < ntile; t++) {
        if (t + 1 < ntile) STAGE(cur ^ 1, (t + 1) * 64);
        COMPUTE(cur);
        __syncthreads();   // drains vmcnt (staging) + lgkmcnt, then barrier
        cur ^= 1;
    }

    #pragma unroll
    for (int mi = 0; mi < MI; mi++) {
        int rl = wm * (16 * MI) + mi * 16 + lhi * 4;
        #pragma unroll
        for (int ni = 0; ni < NI; ni++) {
            int gcol = n0 + wn * (16 * NI) + ni * 16 + l16;
            float bs = (MODE == 0) ? 0.0f : bias[gcol];
            #pragma unroll
            for (int j = 0; j < 4; j++) {
                int grow = m0 + rl + j;
                if (grow >= M) continue;
                float v = acc[mi][ni][j] + bs;
                if (MODE == 1) {
                    float rr = resid[(size_t)grow * N + gcol];
                    ((float*)Cout)[(size_t)grow * N + gcol] = rr + v;
                } else if (MODE == 2) {
                    v = 0.5f * v * (1.0f + erff(v * 0.70710678118654752f));
                    ((ushort*)Cout)[(size_t)grow * N + gcol] = f2bf(v);
                } else {
                    ((ushort*)Cout)[(size_t)grow * N + gcol] = f2bf(v);
                }
            }
        }
    }
}

// ---------------- flash attention (causal), bf16 in/out ----------------
__global__ __launch_bounds__(256) void attn_kernel(
    const ushort* __restrict__ qkv, ushort* __restrict__ out)
{
    __shared__ ushort Ksm[64 * 72];
    __shared__ ushort Vsm[64 * 72];
    __shared__ ushort Psm[4][16 * 72];
    int qt = blockIdx.x, b = blockIdx.y, h = blockIdx.z;
    int tid = threadIdx.x, lane = tid & 63, wave = tid >> 6;
    int l16 = lane & 15, lhi = lane >> 4;

    int qrow = qt*64 + wave*16 + l16;
    bf16x8 qf0 = {}, qf1 = {};
    if (qrow < Tn) {
        const ushort* qp = qkv + (size_t)(b*Tn + qrow) * 3072 + h*64 + lhi*8;
        qf0 = *(const bf16x8*)qp;
        qf1 = *(const bf16x8*)(qp + 32);
    }

    f32x4 o[4];
    #pragma unroll
    for (int i = 0; i < 4; i++) o[i] = (f32x4){0.f,0.f,0.f,0.f};
    float mrun[4] = {-1e30f,-1e30f,-1e30f,-1e30f};
    float sume[4] = {0.f,0.f,0.f,0.f};

    int kr = tid >> 2, cc = (tid & 3) * 16;
    const ushort* kvbase = qkv + (size_t)(b*Tn) * 3072 + h*64 + cc;
    int qg = qt*64 + wave*16 + lhi*4;

    for (int jt = 0; jt <= qt; jt++) {
        int kvr = jt*64 + kr;
        uint4 k0 = make_uint4(0,0,0,0), k1 = k0, v0 = k0, v1 = k0;
        if (kvr < Tn) {
            const ushort* p = kvbase + (size_t)kvr * 3072;
            k0 = *(const uint4*)(p + 1024);
            k1 = *(const uint4*)(p + 1024 + 8);
            v0 = *(const uint4*)(p + 2048);
            v1 = *(const uint4*)(p + 2048 + 8);
        }
        __syncthreads();
        *(uint4*)&Ksm[kr * 72 + cc] = k0;
        *(uint4*)&Ksm[kr * 72 + cc + 8] = k1;
        {
            ushort vv[16];
            *(uint4*)&vv[0] = v0; *(uint4*)&vv[8] = v1;
            #pragma unroll
            for (int i = 0; i < 16; i++) Vsm[(cc + i) * 72 + kr] = vv[i];
        }
        __syncthreads();

        f32x4 s[4];
        #pragma unroll
        for (int ni = 0; ni < 4; ni++) {
            s[ni] = (f32x4){0.f,0.f,0.f,0.f};
            bf16x8 kf0 = *(const bf16x8*)&Ksm[(ni*16 + l16) * 72 + lhi*8];
            bf16x8 kf1 = *(const bf16x8*)&Ksm[(ni*16 + l16) * 72 + lhi*8 + 32];
            s[ni] = __builtin_amdgcn_mfma_f32_16x16x32_bf16(qf0, kf0, s[ni], 0, 0, 0);
            s[ni] = __builtin_amdgcn_mfma_f32_16x16x32_bf16(qf1, kf1, s[ni], 0, 0, 0);
        }

        float pv[4][4];
        #pragma unroll
        for (int j = 0; j < 4; j++) {
            int qgj = qg + j;
            float mx = -1e30f;
            #pragma unroll
            for (int ni = 0; ni < 4; ni++) {
                int kvg = jt*64 + ni*16 + l16;
                float e = (kvg <= qgj && kvg < Tn) ? s[ni][j] * 0.125f : -1e30f;
                pv[ni][j] = e;
                mx = fmaxf(mx, e);
            }
            #pragma unroll
            for (int m = 1; m < 16; m <<= 1) mx = fmaxf(mx, __shfl_xor(mx, m));
            float mnew = fmaxf(mrun[j], mx);
            float fac = expf(mrun[j] - mnew);
            mrun[j] = mnew;
            float rs = 0.f;
            #pragma unroll
            for (int ni = 0; ni < 4; ni++) { pv[ni][j] = expf(pv[ni][j] - mnew); rs += pv[ni][j]; }
            #pragma unroll
            for (int m = 1; m < 16; m <<= 1) rs += __shfl_xor(rs, m);
            sume[j] = sume[j] * fac + rs;
            #pragma unroll
            for (int di = 0; di < 4; di++) o[di][j] *= fac;
        }

        #pragma unroll
        for (int j = 0; j < 4; j++)
            #pragma unroll
            for (int ni = 0; ni < 4; ni++)
                Psm[wave][(lhi*4 + j) * 72 + ni*16 + l16] = f2bf(pv[ni][j]);
        __syncthreads();

        bf16x8 pf0 = *(const bf16x8*)&Psm[wave][l16 * 72 + lhi*8];
        bf16x8 pf1 = *(const bf16x8*)&Psm[wave][l16 * 72 + lhi*8 + 32];
        #pragma unroll
        for (int di = 0; di < 4; di++) {
            bf16x8 vf0 = *(const bf16x8*)&Vsm[(di*16 + l16) * 72 + lhi*8];
            bf16x8 vf1 = *(const bf16x8*)&Vsm[(di*16 + l16) * 72 + lhi*8 + 32];
            o[di] = __builtin_amdgcn_mfma_f32_16x16x32_bf16(pf0, vf0, o[di], 0, 0, 0);
            o[di] = __builtin_amdgcn_mfma_f32_16x16x32_bf16(pf1, vf1, o[di], 0, 0, 0);
        }
    }

    #pragma unroll
    for (int j = 0; j < 4; j++) {
        int qgj = qg + j;
        if (qgj >= Tn) continue;
        float inv = 1.0f / sume[j];
        #pragma unroll
        for (int di = 0; di < 4; di++)
            out[(size_t)(b*Tn + qgj) * Dn + h*64 + di*16 + l16] = f2bf(o[di][j] * inv);
    }
}

// ---------------- final fc on last position ----------------
__global__ __launch_bounds__(256) void fc_kernel(
    const float* __restrict__ x, const float* __restrict__ w,
    const float* __restrict__ bias, float* __restrict__ out)
{
    __shared__ float xs[Dn];
    int b = blockIdx.y;
    int v = blockIdx.x * 256 + threadIdx.x;
    float4 t = ((const float4*)(x + (size_t)(b*Tn + Tn - 1) * Dn))[threadIdx.x];
    ((float4*)xs)[threadIdx.x] = t;
    __syncthreads();
    float acc = bias[v];
    for (int d = 0; d < Dn; d++)
        acc = fmaf(xs[d], w[(size_t)d * Vn + v], acc);
    out[(size_t)b * Vn + v] = acc;
}

extern "C" void kernel_launch(void* const* d_in, const int* in_sizes, int n_in,
                              void* d_out, int out_size, void* d_ws, size_t ws_size,
                              hipStream_t stream)
{
    const int*   text_ids  = (const int*)d_in[0];
    const int*   prompt_ids= (const int*)d_in[1];
    const int*   output_ids= (const int*)d_in[2];
    const float* text_tab  = (const float*)d_in[3];
    const float* prompt_tab= (const float*)d_in[4];
    const float* output_tab= (const float*)d_in[5];
    const float* sep       = (const float*)d_in[6];
    const float* ln1_g     = (const float*)d_in[7];
    const float* ln1_b     = (const float*)d_in[8];
    const float* qkv_w     = (const float*)d_in[9];
    const float* out_w     = (const float*)d_in[10];
    const float* out_b     = (const float*)d_in[11];
    const float* ln2_g     = (const float*)d_in[12];
    const float* ln2_b     = (const float*)d_in[13];
    const float* ff1_w     = (const float*)d_in[14];
    const float* ff1_b     = (const float*)d_in[15];
    const float* ff2_w     = (const float*)d_in[16];
    const float* ff2_b     = (const float*)d_in[17];
    const float* fc_w      = (const float*)d_in[18];
    const float* fc_b      = (const float*)d_in[19];

    char* ws = (char*)d_ws;
    float*  x    = (float*)(ws);                    // [7184][1024] f32 = 29,425,664
    ushort* h    = (ushort*)(ws + 29425664);        // [7424][1024] bf16 = 15,204,352
    ushort* qkv  = (ushort*)(ws + 44630016);        // [7424][3072] bf16 = 45,613,056
    ushort* attn = (ushort*)(ws + 90243072);        // [7424][1024] bf16 = 15,204,352
    ushort* ff1o = (ushort*)(ws + 105447424);       // [7424][4096] bf16 = 60,817,408
    ushort* wT   = (ushort*)(ws + 166264832);       // weights bf16 [N][K]

    const size_t L_STRIDE = 12582912;        // ushorts per layer block
    const size_t OFF_QKV = 0, OFF_OUT = 3145728, OFF_FF1 = 4194304, OFF_FF2 = 8388608;
    const size_t upfront_need = 166264832ULL + 2ULL * L_STRIDE * Ln;  // ~468 MB
    const bool upfront = ws_size >= upfront_need;

    if (upfront) {
        transpose_cast_kernel<<<dim3(48,16,Ln), 256, 0, stream>>>(qkv_w, wT + OFF_QKV, Dn, 3*Dn, (size_t)Dn*3*Dn, L_STRIDE);
        transpose_cast_kernel<<<dim3(16,16,Ln), 256, 0, stream>>>(out_w, wT + OFF_OUT, Dn, Dn,   (size_t)Dn*Dn,   L_STRIDE);
        transpose_cast_kernel<<<dim3(64,16,Ln), 256, 0, stream>>>(ff1_w, wT + OFF_FF1, Dn, FFn,  (size_t)Dn*FFn,  L_STRIDE);
        transpose_cast_kernel<<<dim3(16,64,Ln), 256, 0, stream>>>(ff2_w, wT + OFF_FF2, FFn, Dn,  (size_t)FFn*Dn,  L_STRIDE);
    }

    embed_kernel<<<BT, 256, 0, stream>>>(text_ids, prompt_ids, output_ids,
                                         text_tab, prompt_tab, output_tab, sep, x);

    for (int l = 0; l < Ln; l++) {
        ushort* wb = upfront ? (wT + (size_t)l * L_STRIDE) : wT;
        if (!upfront) {
            transpose_cast_kernel<<<dim3(48,16,1), 256, 0, stream>>>(qkv_w + (size_t)l*Dn*3*Dn, wb + OFF_QKV, Dn, 3*Dn, 0, 0);
            transpose_cast_kernel<<<dim3(16,16,1), 256, 0, stream>>>(out_w + (size_t)l*Dn*Dn,   wb + OFF_OUT, Dn, Dn,   0, 0);
            transpose_cast_kernel<<<dim3(64,16,1), 256, 0, stream>>>(ff1_w + (size_t)l*Dn*FFn,  wb + OFF_FF1, Dn, FFn,  0, 0);
            transpose_cast_kernel<<<dim3(16,64,1), 256, 0, stream>>>(ff2_w + (size_t)l*FFn*Dn,  wb + OFF_FF2, FFn, Dn,  0, 0);
        }
        ln_kernel<<<BT, 256, 0, stream>>>(x, ln1_g + l*Dn, ln1_b + l*Dn, h);
        gemm2_kernel<256,256,2,4,0><<<12*29, 512, 0, stream>>>(
            h, wb + OFF_QKV, nullptr, nullptr, qkv, BT, 3*Dn, Dn, 12);
        attn_kernel<<<dim3(15, Bn, Hn), 256, 0, stream>>>(qkv, attn);
        gemm2_kernel<128,128,2,2,1><<<8*57, 256, 0, stream>>>(
            attn, wb + OFF_OUT, out_b + l*Dn, x, x, BT, Dn, Dn, 8);
        ln_kernel<<<BT, 256, 0, stream>>>(x, ln2_g + l*Dn, ln2_b + l*Dn, h);
        gemm2_kernel<256,256,2,4,2><<<16*29, 512, 0, stream>>>(
            h, wb + OFF_FF1, ff1_b + l*FFn, nullptr, ff1o, BT, FFn, Dn, 16);
        gemm2_kernel<128,128,2,2,1><<<8*57, 256, 0, stream>>>(
            ff1o, wb + OFF_FF2, ff2_b + l*Dn, x, x, BT, Dn, FFn, 8);
    }

    fc_kernel<<<dim3(Vn/256, Bn), 256, 0, stream>>>(x, fc_w, fc_b, (float*)d_out);
}

// Round 5
// 5936.169 us; speedup vs baseline: 1.0374x; 1.0374x over previous
//
#include <hip/hip_runtime.h>
#include <hip/hip_bf16.h>
#include <math.h>

#define Bn 8
#define Tn 898
#define Dn 1024
#define Hn 16
#define DHn 64
#define Ln 12
#define FFn 4096
#define Vn 1024
#define BT (Bn*Tn)   /* 7184 */
#define MP 7424      /* BT padded to 29*256 */

typedef short bf16x8 __attribute__((ext_vector_type(8)));
typedef float f32x4 __attribute__((ext_vector_type(4)));

__device__ __forceinline__ ushort f2bf(float f) {
    union { float f; unsigned u; } c; c.f = f;
    unsigned r = c.u + 0x7fffu + ((c.u >> 16) & 1u);
    return (ushort)(r >> 16);
}

__device__ __forceinline__ void glds16(const void* g, void* l) {
    __builtin_amdgcn_global_load_lds(
        (const __attribute__((address_space(1))) unsigned int*)g,
        (__attribute__((address_space(3))) unsigned int*)l, 16, 0, 0);
}

#define BARRIER() __builtin_amdgcn_s_barrier()
#define VMCNT4() asm volatile("s_waitcnt vmcnt(4)" ::: "memory")
#define VMCNT0() asm volatile("s_waitcnt vmcnt(0)" ::: "memory")
#define SETPRIO(p) __builtin_amdgcn_s_setprio(p)

// ---------------- weight transpose + cast: f32 [K][N] -> bf16 [N][K] ----------------
__global__ __launch_bounds__(256) void transpose_cast_kernel(
    const float* __restrict__ in, ushort* __restrict__ out,
    int K, int N, size_t in_ls, size_t out_ls)
{
    __shared__ ushort t[64][68];
    const float* inp = in + (size_t)blockIdx.z * in_ls;
    ushort* outp = out + (size_t)blockIdx.z * out_ls;
    int n0 = blockIdx.x * 64, k0 = blockIdx.y * 64;
    int tx = threadIdx.x & 63, ty = threadIdx.x >> 6;
    #pragma unroll
    for (int p = 0; p < 16; p++) {
        int kl = p * 4 + ty;
        t[tx][kl] = f2bf(inp[(size_t)(k0 + kl) * N + n0 + tx]);
    }
    __syncthreads();
    int tx4 = threadIdx.x & 15, ty4 = threadIdx.x >> 4;
    #pragma unroll
    for (int p = 0; p < 4; p++) {
        int nl = p * 16 + ty4;
        ushort4 v;
        v.x = t[nl][4*tx4]; v.y = t[nl][4*tx4+1]; v.z = t[nl][4*tx4+2]; v.w = t[nl][4*tx4+3];
        *(ushort4*)&outp[(size_t)(n0 + nl) * K + k0 + 4*tx4] = v;
    }
}

// ---------------- embedding + positional encoding ----------------
__global__ __launch_bounds__(256) void embed_kernel(
    const int* __restrict__ tids, const int* __restrict__ pids, const int* __restrict__ oids,
    const float* __restrict__ ttab, const float* __restrict__ ptab, const float* __restrict__ otab,
    const float* __restrict__ sep, float* __restrict__ x)
{
    int bp = blockIdx.x;
    int b = bp / Tn, pos = bp - b * Tn;
    int d0 = threadIdx.x * 4;
    float4 r;
    if (pos == 128 || pos == 385) {
        r = *(const float4*)(sep + d0);
    } else {
        int t; int id; const float* tab;
        if (pos < 128)      { t = pos;       id = tids[b*128 + t]; tab = ttab; }
        else if (pos < 385) { t = pos - 129; id = pids[b*256 + t]; tab = ptab; }
        else                { t = pos - 386; id = oids[b*512 + t]; tab = otab; }
        float4 e = *(const float4*)(tab + (size_t)id * Dn + d0);
        float pe[4];
        #pragma unroll
        for (int i = 0; i < 4; i++) {
            int d = d0 + i;
            int ii = d & 511;
            float omega = expf(-9.210340371976184f * (float)ii * (1.0f/512.0f));
            float ang = (float)t * omega;
            pe[i] = (d < 512) ? sinf(ang) : cosf(ang);
        }
        r.x = e.x + pe[0]; r.y = e.y + pe[1]; r.z = e.z + pe[2]; r.w = e.w + pe[3];
    }
    *(float4*)(x + (size_t)bp * Dn + d0) = r;
}

// ---------------- layernorm fp32 -> bf16 ----------------
__global__ __launch_bounds__(256) void ln_kernel(
    const float* __restrict__ x, const float* __restrict__ g, const float* __restrict__ bt,
    ushort* __restrict__ out)
{
    __shared__ float red[8];
    int row = blockIdx.x, tid = threadIdx.x;
    float4 v = ((const float4*)(x + (size_t)row * Dn))[tid];
    float s = v.x + v.y + v.z + v.w;
    #pragma unroll
    for (int o = 32; o; o >>= 1) s += __shfl_down(s, o);
    if ((tid & 63) == 0) red[tid >> 6] = s;
    __syncthreads();
    float mu = (red[0] + red[1] + red[2] + red[3]) * (1.0f / Dn);
    float d0 = v.x - mu, d1 = v.y - mu, d2 = v.z - mu, d3 = v.w - mu;
    float s2 = d0*d0 + d1*d1 + d2*d2 + d3*d3;
    #pragma unroll
    for (int o = 32; o; o >>= 1) s2 += __shfl_down(s2, o);
    if ((tid & 63) == 0) red[4 + (tid >> 6)] = s2;
    __syncthreads();
    float var = (red[4] + red[5] + red[6] + red[7]) * (1.0f / Dn);
    float rstd = rsqrtf(var + 1e-5f);
    float4 gg = ((const float4*)g)[tid];
    float4 bb = ((const float4*)bt)[tid];
    ushort4 o4;
    o4.x = f2bf(d0 * rstd * gg.x + bb.x);
    o4.y = f2bf(d1 * rstd * gg.y + bb.y);
    o4.z = f2bf(d2 * rstd * gg.z + bb.z);
    o4.w = f2bf(d3 * rstd * gg.w + bb.w);
    ((ushort4*)(out + (size_t)row * Dn))[tid] = o4;
}

// ---------------- 8-phase-style pipelined GEMM: C = A(bf16 [M][K]) @ Bw(bf16 [N][K])^T ------
// T2 XOR-swizzle (chunk ^= row&7, pre-swizzled global src + swizzled ds_read),
// T3 per-phase {ds-read || stage -> barrier -> MFMA -> barrier}, T4 counted vmcnt(4)
// (vmcnt(0) once at the tail where no stageA follows -- fixes the last-tile B race),
// T5 setprio around MFMA.
// MODE 0: store bf16; MODE 1: f32 = resid + AB + bias; MODE 2: bf16 = gelu(AB + bias)
template<int BM, int BN, int WM, int WN, int MODE>
__global__ __launch_bounds__(512, 2) void gemm8_kernel(
    const ushort* __restrict__ A, const ushort* __restrict__ Bw,
    const float* __restrict__ bias, const float* __restrict__ resid,
    void* __restrict__ Cout, int M, int N, int K, int nx)
{
    constexpr int MI = BM / WM / 16;
    constexpr int NI = BN / WN / 16;
    constexpr int MH = MI / 2, NH = NI / 2;
    constexpr int GA = BM / 128;          // glds per thread per A half-unit
    constexpr int GB = BN / 128;
    constexpr int RA = BM / 2, RB = BN / 2;

    __shared__ ushort sA0[BM * 64], sB0[BN * 64];
    __shared__ ushort sA1[BM * 64], sB1[BN * 64];

    int tid = threadIdx.x, lane = tid & 63, wv = tid >> 6;
    int wm = wv / WN, wn = wv % WN;
    int l16 = lane & 15, lhi = lane >> 4;

    // bijective XCD-chunked swizzle
    int nb = gridDim.x, bid = blockIdx.x;
    int qq = nb >> 3, rr8 = nb & 7;
    int xcd = bid & 7, idx = bid >> 3;
    int wg = (xcd < rr8 ? xcd * (qq + 1) : rr8 * (qq + 1) + (xcd - rr8) * qq) + idx;
    int mt = wg / nx, ntt = wg - mt * nx;
    int m0 = mt * BM, n0 = ntt * BN;

    f32x4 acc[MI][NI];
    #pragma unroll
    for (int i = 0; i < MI; i++)
        #pragma unroll
        for (int j = 0; j < NI; j++) acc[i][j] = (f32x4){0.f, 0.f, 0.f, 0.f};

    // staging: lane covers row (base + lane>>3), swizzled 16B chunk (lane&7)^(lane>>3)
    int srow = lane >> 3;
    int schk = (lane & 7) ^ srow;
    const char* Abase = (const char*)A + (size_t)m0 * K * 2 + schk * 16;
    const char* Bbase = (const char*)Bw + (size_t)n0 * K * 2 + schk * 16;

    auto stageA = [&](ushort* dst, int t2) {
        size_t ko = (size_t)t2 * 128;
        #pragma unroll
        for (int h = 0; h < 2; h++)
            #pragma unroll
            for (int j = 0; j < GA; j++) {
                int rrow = h * RA + wv * (RA / 8) + j * 8;
                glds16(Abase + (size_t)(rrow + srow) * (K * 2) + ko, dst + rrow * 64);
            }
    };
    auto stageB = [&](ushort* dst, int h, int t1) {
        size_t ko = (size_t)t1 * 128;
        #pragma unroll
        for (int j = 0; j < GB; j++) {
            int rrow = h * RB + wv * (RB / 8) + j * 8;
            glds16(Bbase + (size_t)(rrow + srow) * (K * 2) + ko, dst + rrow * 64);
        }
    };

    // fragment reads (swizzled): chunk = (ks*4+lhi) ^ (row&7)
    int rbA = wm * (MI * 16) + l16;
    int rbB = wn * (NI * 16) + l16;
    int sc0 = ((lhi) ^ (l16 & 7)) * 8;
    int sc1 = ((4 + lhi) ^ (l16 & 7)) * 8;

    bf16x8 af[MH][2], bf0[NH][2], bf1[NH][2];

    auto ldA = [&](const ushort* S, int mh) {
        #pragma unroll
        for (int mi = 0; mi < MH; mi++) {
            int row = rbA + (mh * MH + mi) * 16;
            af[mi][0] = *(const bf16x8*)&S[row * 64 + sc0];
            af[mi][1] = *(const bf16x8*)&S[row * 64 + sc1];
        }
    };
    auto ldB = [&](bf16x8 (&bf)[NH][2], const ushort* S, int nh) {
        #pragma unroll
        for (int ni = 0; ni < NH; ni++) {
            int row = rbB + (nh * NH + ni) * 16;
            bf[ni][0] = *(const bf16x8*)&S[row * 64 + sc0];
            bf[ni][1] = *(const bf16x8*)&S[row * 64 + sc1];
        }
    };
    auto MM = [&](int mh, int nh, bf16x8 (&bf)[NH][2]) {
        #pragma unroll
        for (int ks = 0; ks < 2; ks++)
            #pragma unroll
            for (int mi = 0; mi < MH; mi++)
                #pragma unroll
                for (int ni = 0; ni < NH; ni++)
                    acc[mh*MH+mi][nh*NH+ni] = __builtin_amdgcn_mfma_f32_16x16x32_bf16(
                        af[mi][ks], bf[ni][ks], acc[mh*MH+mi][nh*NH+ni], 0, 0, 0);
    };

    int ntile = K >> 6;

    auto tile = [&](const ushort* AS, const ushort* BS, ushort* ASw, ushort* BSo, int t) {
        bool sb = (t + 1) < ntile;
        bool sa = (t + 2) < ntile;
        // P0: read A(mh0), B(nh0); stage B0(t+1)
        ldA(AS, 0); ldB(bf0, BS, 0);
        if (sb) stageB(BSo, 0, t + 1);
        BARRIER();
        SETPRIO(1); MM(0, 0, bf0); SETPRIO(0);
        BARRIER();
        // P1: read B(nh1); stage B1(t+1)
        ldB(bf1, BS, 1);
        if (sb) stageB(BSo, 1, t + 1);
        BARRIER();
        SETPRIO(1); MM(0, 1, bf1); SETPRIO(0);
        BARRIER();
        // P2: read A(mh1)
        ldA(AS, 1);
        BARRIER();
        SETPRIO(1); MM(1, 1, bf1); SETPRIO(0);
        BARRIER();
        // P3: stage A(t+2); counted drain while stageA refills the queue.
        // When no stageA follows (tail), the 4 in-flight loads would be the
        // NEXT tile's B -- must drain fully (this was the round-4 race).
        if (sa) {
            stageA(ASw, t + 2);
            SETPRIO(1); MM(1, 0, bf0); SETPRIO(0);
            VMCNT4();
        } else {
            SETPRIO(1); MM(1, 0, bf0); SETPRIO(0);
            VMCNT0();
        }
        BARRIER();
    };

    // prologue: A(0), B(0), A(1); wait all but the 4 A(1) loads
    stageA(sA0, 0);
    stageB(sB0, 0, 0); stageB(sB0, 1, 0);
    if (ntile > 1) stageA(sA1, 1);
    VMCNT4();
    BARRIER();

    for (int t = 0; t < ntile; t += 2) {
        tile(sA0, sB0, sA0, sB1, t);
        tile(sA1, sB1, sA1, sB0, t + 1);
    }

    // epilogue
    #pragma unroll
    for (int mi = 0; mi < MI; mi++) {
        int rl = wm * (MI * 16) + mi * 16 + lhi * 4;
        #pragma unroll
        for (int ni = 0; ni < NI; ni++) {
            int gcol = n0 + wn * (NI * 16) + ni * 16 + l16;
            float bs = (MODE == 0) ? 0.0f : bias[gcol];
            #pragma unroll
            for (int j = 0; j < 4; j++) {
                int grow = m0 + rl + j;
                if (grow >= M) continue;
                float v = acc[mi][ni][j] + bs;
                if (MODE == 1) {
                    float rv = resid[(size_t)grow * N + gcol];
                    ((float*)Cout)[(size_t)grow * N + gcol] = rv + v;
                } else if (MODE == 2) {
                    v = 0.5f * v * (1.0f + erff(v * 0.70710678118654752f));
                    ((ushort*)Cout)[(size_t)grow * N + gcol] = f2bf(v);
                } else {
                    ((ushort*)Cout)[(size_t)grow * N + gcol] = f2bf(v);
                }
            }
        }
    }
}

// ---------------- flash attention (causal), bf16 in/out ----------------
__global__ __launch_bounds__(256) void attn_kernel(
    const ushort* __restrict__ qkv, ushort* __restrict__ out)
{
    __shared__ ushort Ksm[64 * 72];
    __shared__ ushort Vsm[64 * 72];
    __shared__ ushort Psm[4][16 * 72];
    int qt = blockIdx.x, b = blockIdx.y, h = blockIdx.z;
    int tid = threadIdx.x, lane = tid & 63, wave = tid >> 6;
    int l16 = lane & 15, lhi = lane >> 4;

    int qrow = qt*64 + wave*16 + l16;
    bf16x8 qf0 = {}, qf1 = {};
    if (qrow < Tn) {
        const ushort* qp = qkv + (size_t)(b*Tn + qrow) * 3072 + h*64 + lhi*8;
        qf0 = *(const bf16x8*)qp;
        qf1 = *(const bf16x8*)(qp + 32);
    }

    f32x4 o[4];
    #pragma unroll
    for (int i = 0; i < 4; i++) o[i] = (f32x4){0.f,0.f,0.f,0.f};
    float mrun[4] = {-1e30f,-1e30f,-1e30f,-1e30f};
    float sume[4] = {0.f,0.f,0.f,0.f};

    int kr = tid >> 2, cc = (tid & 3) * 16;
    const ushort* kvbase = qkv + (size_t)(b*Tn) * 3072 + h*64 + cc;
    int qg = qt*64 + wave*16 + lhi*4;

    for (int jt = 0; jt <= qt; jt++) {
        int kvr = jt*64 + kr;
        uint4 k0 = make_uint4(0,0,0,0), k1 = k0, v0 = k0, v1 = k0;
        if (kvr < Tn) {
            const ushort* p = kvbase + (size_t)kvr * 3072;
            k0 = *(const uint4*)(p + 1024);
            k1 = *(const uint4*)(p + 1024 + 8);
            v0 = *(const uint4*)(p + 2048);
            v1 = *(const uint4*)(p + 2048 + 8);
        }
        __syncthreads();
        *(uint4*)&Ksm[kr * 72 + cc] = k0;
        *(uint4*)&Ksm[kr * 72 + cc + 8] = k1;
        {
            ushort vv[16];
            *(uint4*)&vv[0] = v0; *(uint4*)&vv[8] = v1;
            #pragma unroll
            for (int i = 0; i < 16; i++) Vsm[(cc + i) * 72 + kr] = vv[i];
        }
        __syncthreads();

        f32x4 s[4];
        #pragma unroll
        for (int ni = 0; ni < 4; ni++) {
            s[ni] = (f32x4){0.f,0.f,0.f,0.f};
            bf16x8 kf0 = *(const bf16x8*)&Ksm[(ni*16 + l16) * 72 + lhi*8];
            bf16x8 kf1 = *(const bf16x8*)&Ksm[(ni*16 + l16) * 72 + lhi*8 + 32];
            s[ni] = __builtin_amdgcn_mfma_f32_16x16x32_bf16(qf0, kf0, s[ni], 0, 0, 0);
            s[ni] = __builtin_amdgcn_mfma_f32_16x16x32_bf16(qf1, kf1, s[ni], 0, 0, 0);
        }

        float pv[4][4];
        #pragma unroll
        for (int j = 0; j < 4; j++) {
            int qgj = qg + j;
            float mx = -1e30f;
            #pragma unroll
            for (int ni = 0; ni < 4; ni++) {
                int kvg = jt*64 + ni*16 + l16;
                float e = (kvg <= qgj && kvg < Tn) ? s[ni][j] * 0.125f : -1e30f;
                pv[ni][j] = e;
                mx = fmaxf(mx, e);
            }
            #pragma unroll
            for (int m = 1; m < 16; m <<= 1) mx = fmaxf(mx, __shfl_xor(mx, m));
            float mnew = fmaxf(mrun[j], mx);
            float fac = expf(mrun[j] - mnew);
            mrun[j] = mnew;
            float rs = 0.f;
            #pragma unroll
            for (int ni = 0; ni < 4; ni++) { pv[ni][j] = expf(pv[ni][j] - mnew); rs += pv[ni][j]; }
            #pragma unroll
            for (int m = 1; m < 16; m <<= 1) rs += __shfl_xor(rs, m);
            sume[j] = sume[j] * fac + rs;
            #pragma unroll
            for (int di = 0; di < 4; di++) o[di][j] *= fac;
        }

        #pragma unroll
        for (int j = 0; j < 4; j++)
            #pragma unroll
            for (int ni = 0; ni < 4; ni++)
                Psm[wave][(lhi*4 + j) * 72 + ni*16 + l16] = f2bf(pv[ni][j]);
        __syncthreads();

        bf16x8 pf0 = *(const bf16x8*)&Psm[wave][l16 * 72 + lhi*8];
        bf16x8 pf1 = *(const bf16x8*)&Psm[wave][l16 * 72 + lhi*8 + 32];
        #pragma unroll
        for (int di = 0; di < 4; di++) {
            bf16x8 vf0 = *(const bf16x8*)&Vsm[(di*16 + l16) * 72 + lhi*8];
            bf16x8 vf1 = *(const bf16x8*)&Vsm[(di*16 + l16) * 72 + lhi*8 + 32];
            o[di] = __builtin_amdgcn_mfma_f32_16x16x32_bf16(pf0, vf0, o[di], 0, 0, 0);
            o[di] = __builtin_amdgcn_mfma_f32_16x16x32_bf16(pf1, vf1, o[di], 0, 0, 0);
        }
    }

    #pragma unroll
    for (int j = 0; j < 4; j++) {
        int qgj = qg + j;
        if (qgj >= Tn) continue;
        float inv = 1.0f / sume[j];
        #pragma unroll
        for (int di = 0; di < 4; di++)
            out[(size_t)(b*Tn + qgj) * Dn + h*64 + di*16 + l16] = f2bf(o[di][j] * inv);
    }
}

// ---------------- final fc on last position ----------------
__global__ __launch_bounds__(256) void fc_kernel(
    const float* __restrict__ x, const float* __restrict__ w,
    const float* __restrict__ bias, float* __restrict__ out)
{
    __shared__ float xs[Dn];
    int b = blockIdx.y;
    int v = blockIdx.x * 256 + threadIdx.x;
    float4 t = ((const float4*)(x + (size_t)(b*Tn + Tn - 1) * Dn))[threadIdx.x];
    ((float4*)xs)[threadIdx.x] = t;
    __syncthreads();
    float acc = bias[v];
    for (int d = 0; d < Dn; d++)
        acc = fmaf(xs[d], w[(size_t)d * Vn + v], acc);
    out[(size_t)b * Vn + v] = acc;
}

extern "C" void kernel_launch(void* const* d_in, const int* in_sizes, int n_in,
                              void* d_out, int out_size, void* d_ws, size_t ws_size,
                              hipStream_t stream)
{
    const int*   text_ids  = (const int*)d_in[0];
    const int*   prompt_ids= (const int*)d_in[1];
    const int*   output_ids= (const int*)d_in[2];
    const float* text_tab  = (const float*)d_in[3];
    const float* prompt_tab= (const float*)d_in[4];
    const float* output_tab= (const float*)d_in[5];
    const float* sep       = (const float*)d_in[6];
    const float* ln1_g     = (const float*)d_in[7];
    const float* ln1_b     = (const float*)d_in[8];
    const float* qkv_w     = (const float*)d_in[9];
    const float* out_w     = (const float*)d_in[10];
    const float* out_b     = (const float*)d_in[11];
    const float* ln2_g     = (const float*)d_in[12];
    const float* ln2_b     = (const float*)d_in[13];
    const float* ff1_w     = (const float*)d_in[14];
    const float* ff1_b     = (const float*)d_in[15];
    const float* ff2_w     = (const float*)d_in[16];
    const float* ff2_b     = (const float*)d_in[17];
    const float* fc_w      = (const float*)d_in[18];
    const float* fc_b      = (const float*)d_in[19];

    char* ws = (char*)d_ws;
    float*  x    = (float*)(ws);                    // [7184][1024] f32 = 29,425,664
    ushort* h    = (ushort*)(ws + 29425664);        // [7424][1024] bf16 = 15,204,352
    ushort* qkv  = (ushort*)(ws + 44630016);        // [7424][3072] bf16 = 45,613,056
    ushort* attn = (ushort*)(ws + 90243072);        // [7424][1024] bf16 = 15,204,352
    ushort* ff1o = (ushort*)(ws + 105447424);       // [7424][4096] bf16 = 60,817,408
    ushort* wT   = (ushort*)(ws + 166264832);       // weights bf16 [N][K]

    const size_t L_STRIDE = 12582912;        // ushorts per layer block
    const size_t OFF_QKV = 0, OFF_OUT = 3145728, OFF_FF1 = 4194304, OFF_FF2 = 8388608;
    const size_t upfront_need = 166264832ULL + 2ULL * L_STRIDE * Ln;
    const bool upfront = ws_size >= upfront_need;

    if (upfront) {
        transpose_cast_kernel<<<dim3(48,16,Ln), 256, 0, stream>>>(qkv_w, wT + OFF_QKV, Dn, 3*Dn, (size_t)Dn*3*Dn, L_STRIDE);
        transpose_cast_kernel<<<dim3(16,16,Ln), 256, 0, stream>>>(out_w, wT + OFF_OUT, Dn, Dn,   (size_t)Dn*Dn,   L_STRIDE);
        transpose_cast_kernel<<<dim3(64,16,Ln), 256, 0, stream>>>(ff1_w, wT + OFF_FF1, Dn, FFn,  (size_t)Dn*FFn,  L_STRIDE);
        transpose_cast_kernel<<<dim3(16,64,Ln), 256, 0, stream>>>(ff2_w, wT + OFF_FF2, FFn, Dn,  (size_t)FFn*Dn,  L_STRIDE);
    }

    embed_kernel<<<BT, 256, 0, stream>>>(text_ids, prompt_ids, output_ids,
                                         text_tab, prompt_tab, output_tab, sep, x);

    for (int l = 0; l < Ln; l++) {
        ushort* wb = upfront ? (wT + (size_t)l * L_STRIDE) : wT;
        if (!upfront) {
            transpose_cast_kernel<<<dim3(48,16,1), 256, 0, stream>>>(qkv_w + (size_t)l*Dn*3*Dn, wb + OFF_QKV, Dn, 3*Dn, 0, 0);
            transpose_cast_kernel<<<dim3(16,16,1), 256, 0, stream>>>(out_w + (size_t)l*Dn*Dn,   wb + OFF_OUT, Dn, Dn,   0, 0);
            transpose_cast_kernel<<<dim3(64,16,1), 256, 0, stream>>>(ff1_w + (size_t)l*Dn*FFn,  wb + OFF_FF1, Dn, FFn,  0, 0);
            transpose_cast_kernel<<<dim3(16,64,1), 256, 0, stream>>>(ff2_w + (size_t)l*FFn*Dn,  wb + OFF_FF2, FFn, Dn,  0, 0);
        }
        ln_kernel<<<BT, 256, 0, stream>>>(x, ln1_g + l*Dn, ln1_b + l*Dn, h);
        gemm8_kernel<256,256,2,4,0><<<29*12, 512, 0, stream>>>(
            h, wb + OFF_QKV, nullptr, nullptr, qkv, BT, 3*Dn, Dn, 12);
        attn_kernel<<<dim3(15, Bn, Hn), 256, 0, stream>>>(qkv, attn);
        gemm8_kernel<256,128,4,2,1><<<29*8, 512, 0, stream>>>(
            attn, wb + OFF_OUT, out_b + l*Dn, x, x, BT, Dn, Dn, 8);
        ln_kernel<<<BT, 256, 0, stream>>>(x, ln2_g + l*Dn, ln2_b + l*Dn, h);
        gemm8_kernel<256,256,2,4,2><<<29*16, 512, 0, stream>>>(
            h, wb + OFF_FF1, ff1_b + l*FFn, nullptr, ff1o, BT, FFn, Dn, 16);
        gemm8_kernel<256,128,4,2,1><<<29*8, 512, 0, stream>>>(
            ff1o, wb + OFF_FF2, ff2_b + l*Dn, x, x, BT, Dn, FFn, 8);
    }

    fc_kernel<<<dim3(Vn/256, Bn), 256, 0, stream>>>(x, fc_w, fc_b, (float*)d_out);
}